// Round 2
// baseline (3679.221 us; speedup 1.0000x reference)
//
#include <hip/hip_runtime.h>
#include <math.h>

constexpr int L_LEVELS = 16;
constexpr unsigned TABLE_SIZE = 1u << 19;
constexpr unsigned TMASK = TABLE_SIZE - 1u;

struct EncP {
    float scale[L_LEVELS];
    unsigned res[L_LEVELS];
};

__global__ __launch_bounds__(256, 6) void enc_mlp_kernel(
    const float* __restrict__ x,
    const float* __restrict__ table,
    const float* __restrict__ W1,
    const float* __restrict__ W2,
    const float* __restrict__ W3,
    float* __restrict__ out,
    EncP p)
{
    const int tid = threadIdx.x;
    const int n = blockIdx.x * 256 + tid;

    const float x0 = x[n * 3 + 0];
    const float x1 = x[n * 3 + 1];
    const float x2 = x[n * 3 + 2];

    // ---------------- grid encode: 16 levels, 8 corners each ----------------
    float xc[32];
#pragma unroll
    for (int l = 0; l < L_LEVELS; ++l) {
        const float s = p.scale[l];
        const unsigned r = p.res[l];
        const unsigned r2 = r * r;               // uint32 wrap, matches int32 wrap bits

        float px = x0 * s + 0.5f;
        float py = x1 * s + 0.5f;
        float pz = x2 * s + 0.5f;
        float gx = floorf(px), gy = floorf(py), gz = floorf(pz);
        float fx = px - gx, fy = py - gy, fz = pz - gz;
        unsigned ix = (unsigned)(int)gx;
        unsigned iy = (unsigned)(int)gy;
        unsigned iz = (unsigned)(int)gz;
        unsigned base = ix + iy * r + iz * r2;   // wraps like int32

        const float* tl = table + (size_t)l * (size_t)TABLE_SIZE * 2u;
        float a0 = 0.f, a1 = 0.f;
#pragma unroll
        for (int c = 0; c < 8; ++c) {
            // offs row order: i outer (x), then j (y), then k (z)
            const unsigned dx = (c >> 2) & 1u;
            const unsigned dy = (c >> 1) & 1u;
            const unsigned dz = c & 1u;
            unsigned lin = base + dx + dy * r + dz * r2;   // uint32 wrap == int32 wrap
            unsigned idx = lin & TMASK;                    // == python floor-mod 2^19
            const float2 f = *(const float2*)(tl + 2u * idx);
            const float w = (dx ? fx : 1.f - fx) * (dy ? fy : 1.f - fy) * (dz ? fz : 1.f - fz);
            a0 += w * f.x;
            a1 += w * f.y;
        }
        xc[2 * l + 0] = a0;
        xc[2 * l + 1] = a1;
    }

    // ---------------- MLP: 32 -> 64 -> 64 -> 32, ReLU ----------------
    // t_code is all zeros, so only rows 0..31 of W1 matter.
    float h1[64];
#pragma unroll
    for (int j = 0; j < 64; ++j) h1[j] = 0.f;
#pragma unroll
    for (int i = 0; i < 32; ++i) {
        const float v = xc[i];
#pragma unroll
        for (int j = 0; j < 64; ++j) h1[j] = fmaf(v, W1[i * 64 + j], h1[j]);
    }
#pragma unroll
    for (int j = 0; j < 64; ++j) h1[j] = fmaxf(h1[j], 0.f);

    float h2[64];
#pragma unroll
    for (int j = 0; j < 64; ++j) h2[j] = 0.f;
#pragma unroll
    for (int i = 0; i < 64; ++i) {
        const float v = h1[i];
#pragma unroll
        for (int j = 0; j < 64; ++j) h2[j] = fmaf(v, W2[i * 64 + j], h2[j]);
    }
#pragma unroll
    for (int j = 0; j < 64; ++j) h2[j] = fmaxf(h2[j], 0.f);

    float o[32];
#pragma unroll
    for (int j = 0; j < 32; ++j) o[j] = 0.f;
#pragma unroll
    for (int i = 0; i < 64; ++i) {
        const float v = h2[i];
#pragma unroll
        for (int j = 0; j < 32; ++j) o[j] = fmaf(v, W3[i * 32 + j], o[j]);
    }

    // ---------------- direct stores: 8 x float4, thread-contiguous ----------
    // Thread n owns out[n*32 .. n*32+31]; 8 consecutive 16B stores fill each
    // 64B line from a single thread -> L2 write-combines, no LDS needed.
    float* ob = out + (size_t)n * 32;
#pragma unroll
    for (int k = 0; k < 8; ++k) {
        float4 v;
        v.x = fmaxf(o[4 * k + 0], 0.f);
        v.y = fmaxf(o[4 * k + 1], 0.f);
        v.z = fmaxf(o[4 * k + 2], 0.f);
        v.w = fmaxf(o[4 * k + 3], 0.f);
        *(float4*)(ob + 4 * k) = v;
    }
}

extern "C" void kernel_launch(void* const* d_in, const int* in_sizes, int n_in,
                              void* d_out, int out_size, void* d_ws, size_t ws_size,
                              hipStream_t stream) {
    (void)in_sizes; (void)n_in; (void)d_ws; (void)ws_size; (void)out_size;

    const float* x     = (const float*)d_in[0];
    // d_in[1] = t : unused (t_code is zeros)
    const float* table = (const float*)d_in[2];
    const float* W1    = (const float*)d_in[3];
    const float* W2    = (const float*)d_in[4];
    const float* W3    = (const float*)d_in[5];
    float* out = (float*)d_out;

    EncP p;
    const double b = exp(log(2048.0 / 16.0) / 15.0);
    for (int l = 0; l < L_LEVELS; ++l) {
        const float s = (float)(16.0 * pow(b, (double)l) - 1.0);  // matches np float32 cast
        p.scale[l] = s;
        p.res[l] = (unsigned)((long long)s) + 1u;                 // matches astype(int64)+1
    }

    hipLaunchKernelGGL(enc_mlp_kernel, dim3(1048576 / 256), dim3(256), 0, stream,
                       x, table, W1, W2, W3, out, p);
}

// Round 3
// 878.284 us; speedup vs baseline: 4.1891x; 4.1891x over previous
//
#include <hip/hip_runtime.h>
#include <math.h>

constexpr int L_LEVELS = 16;
constexpr unsigned TABLE_SIZE = 1u << 19;
constexpr unsigned TMASK = TABLE_SIZE - 1u;
constexpr int N_PTS = 1048576;

struct EncP {
    float scale[L_LEVELS];
    unsigned res[L_LEVELS];
};

// ---------------------------------------------------------------------------
// Kernel 1: grid encode, one (point, level) per thread. Tiny register state ->
// ~8 waves/SIMD. Level-phased + XCD-pinned via blockIdx decode so each XCD
// streams through one 4MB table slice at a time (fits its private L2).
// ws layout: [L][N][2] floats, lane-coalesced float2 stores.
// ---------------------------------------------------------------------------
__global__ __launch_bounds__(256) void encode_kernel(
    const float* __restrict__ x,
    const float* __restrict__ table,
    float* __restrict__ ws,
    EncP p)
{
    const unsigned bid = blockIdx.x;
    // 65536 blocks: xcd-heuristic decode. bid%8 ~ XCD (round-robin dispatch);
    // each XCD does level xcd for 4096 point-blocks, then level xcd+8.
    const unsigned level = (bid & 7u) + 8u * (bid >> 15);
    const unsigned pblk  = (bid >> 3) & 4095u;
    const unsigned n = pblk * 256u + threadIdx.x;

    const float x0 = x[n * 3 + 0];
    const float x1 = x[n * 3 + 1];
    const float x2 = x[n * 3 + 2];

    const float s = p.scale[level];
    const unsigned r = p.res[level];
    const unsigned r2 = r * r;                   // uint32 wrap == int32 wrap bits

    float px = x0 * s + 0.5f;
    float py = x1 * s + 0.5f;
    float pz = x2 * s + 0.5f;
    float gx = floorf(px), gy = floorf(py), gz = floorf(pz);
    float fx = px - gx, fy = py - gy, fz = pz - gz;
    unsigned ix = (unsigned)(int)gx;
    unsigned iy = (unsigned)(int)gy;
    unsigned iz = (unsigned)(int)gz;
    unsigned base = ix + iy * r + iz * r2;

    const float* tl = table + (size_t)level * (size_t)TABLE_SIZE * 2u;
    float a0 = 0.f, a1 = 0.f;
#pragma unroll
    for (int c = 0; c < 8; ++c) {
        const unsigned dx = (c >> 2) & 1u;
        const unsigned dy = (c >> 1) & 1u;
        const unsigned dz = c & 1u;
        unsigned lin = base + dx + dy * r + dz * r2;
        unsigned idx = lin & TMASK;              // == python floor-mod 2^19
        const float2 f = *(const float2*)(tl + 2u * idx);
        const float w = (dx ? fx : 1.f - fx) * (dy ? fy : 1.f - fy) * (dz ? fz : 1.f - fz);
        a0 += w * f.x;
        a1 += w * f.y;
    }
    // coalesced: consecutive lanes -> consecutive float2
    *(float2*)(ws + ((size_t)level * N_PTS + n) * 2u) = make_float2(a0, a1);
}

// ---------------------------------------------------------------------------
// Kernel 2: MLP 32->64->64->32 (fp32 VALU, AGPR-backed arrays), reads xc from
// ws coalesced, writes out via padded-LDS transpose (proven 134MB WRITE_SIZE).
// ---------------------------------------------------------------------------
__global__ __launch_bounds__(256) void mlp_kernel(
    const float* __restrict__ ws,
    const float* __restrict__ W1,
    const float* __restrict__ W2,
    const float* __restrict__ W3,
    float* __restrict__ out)
{
    __shared__ float lds[256 * 33];
    const int tid = threadIdx.x;
    const unsigned n = blockIdx.x * 256u + tid;

    float xc[32];
#pragma unroll
    for (int l = 0; l < L_LEVELS; ++l) {
        const float2 v = *(const float2*)(ws + ((size_t)l * N_PTS + n) * 2u);
        xc[2 * l + 0] = v.x;
        xc[2 * l + 1] = v.y;
    }

    float h1[64];
#pragma unroll
    for (int j = 0; j < 64; ++j) h1[j] = 0.f;
#pragma unroll
    for (int i = 0; i < 32; ++i) {
        const float v = xc[i];
#pragma unroll
        for (int j = 0; j < 64; ++j) h1[j] = fmaf(v, W1[i * 64 + j], h1[j]);
    }
#pragma unroll
    for (int j = 0; j < 64; ++j) h1[j] = fmaxf(h1[j], 0.f);

    float h2[64];
#pragma unroll
    for (int j = 0; j < 64; ++j) h2[j] = 0.f;
#pragma unroll
    for (int i = 0; i < 64; ++i) {
        const float v = h1[i];
#pragma unroll
        for (int j = 0; j < 64; ++j) h2[j] = fmaf(v, W2[i * 64 + j], h2[j]);
    }
#pragma unroll
    for (int j = 0; j < 64; ++j) h2[j] = fmaxf(h2[j], 0.f);

    float o[32];
#pragma unroll
    for (int j = 0; j < 32; ++j) o[j] = 0.f;
#pragma unroll
    for (int i = 0; i < 64; ++i) {
        const float v = h2[i];
#pragma unroll
        for (int j = 0; j < 32; ++j) o[j] = fmaf(v, W3[i * 32 + j], o[j]);
    }

#pragma unroll
    for (int j = 0; j < 32; ++j) lds[tid * 33 + j] = fmaxf(o[j], 0.f);
    __syncthreads();

    float* outb = out + (size_t)blockIdx.x * 8192;
#pragma unroll
    for (int k = 0; k < 8; ++k) {
        const int e = k * 1024 + tid * 4;
        float4 v;
        v.x = lds[((e + 0) >> 5) * 33 + ((e + 0) & 31)];
        v.y = lds[((e + 1) >> 5) * 33 + ((e + 1) & 31)];
        v.z = lds[((e + 2) >> 5) * 33 + ((e + 2) & 31)];
        v.w = lds[((e + 3) >> 5) * 33 + ((e + 3) & 31)];
        *(float4*)(outb + e) = v;
    }
}

// ---------------------------------------------------------------------------
// Fallback: round-1 monolithic kernel (used only if ws too small).
// ---------------------------------------------------------------------------
__global__ __launch_bounds__(256) void mono_kernel(
    const float* __restrict__ x, const float* __restrict__ table,
    const float* __restrict__ W1, const float* __restrict__ W2,
    const float* __restrict__ W3, float* __restrict__ out, EncP p)
{
    __shared__ float lds[256 * 33];
    const int tid = threadIdx.x;
    const int n = blockIdx.x * 256 + tid;
    const float x0 = x[n * 3 + 0], x1 = x[n * 3 + 1], x2 = x[n * 3 + 2];
    float xc[32];
#pragma unroll
    for (int l = 0; l < L_LEVELS; ++l) {
        const float s = p.scale[l];
        const unsigned r = p.res[l], r2 = r * r;
        float px = x0 * s + 0.5f, py = x1 * s + 0.5f, pz = x2 * s + 0.5f;
        float gx = floorf(px), gy = floorf(py), gz = floorf(pz);
        float fx = px - gx, fy = py - gy, fz = pz - gz;
        unsigned base = (unsigned)(int)gx + (unsigned)(int)gy * r + (unsigned)(int)gz * r2;
        const float* tl = table + (size_t)l * (size_t)TABLE_SIZE * 2u;
        float a0 = 0.f, a1 = 0.f;
#pragma unroll
        for (int c = 0; c < 8; ++c) {
            const unsigned dx = (c >> 2) & 1u, dy = (c >> 1) & 1u, dz = c & 1u;
            unsigned idx = (base + dx + dy * r + dz * r2) & TMASK;
            const float2 f = *(const float2*)(tl + 2u * idx);
            const float w = (dx ? fx : 1.f - fx) * (dy ? fy : 1.f - fy) * (dz ? fz : 1.f - fz);
            a0 += w * f.x; a1 += w * f.y;
        }
        xc[2 * l] = a0; xc[2 * l + 1] = a1;
    }
    float h1[64];
#pragma unroll
    for (int j = 0; j < 64; ++j) h1[j] = 0.f;
#pragma unroll
    for (int i = 0; i < 32; ++i) {
        const float v = xc[i];
#pragma unroll
        for (int j = 0; j < 64; ++j) h1[j] = fmaf(v, W1[i * 64 + j], h1[j]);
    }
#pragma unroll
    for (int j = 0; j < 64; ++j) h1[j] = fmaxf(h1[j], 0.f);
    float h2[64];
#pragma unroll
    for (int j = 0; j < 64; ++j) h2[j] = 0.f;
#pragma unroll
    for (int i = 0; i < 64; ++i) {
        const float v = h1[i];
#pragma unroll
        for (int j = 0; j < 64; ++j) h2[j] = fmaf(v, W2[i * 64 + j], h2[j]);
    }
#pragma unroll
    for (int j = 0; j < 64; ++j) h2[j] = fmaxf(h2[j], 0.f);
    float o[32];
#pragma unroll
    for (int j = 0; j < 32; ++j) o[j] = 0.f;
#pragma unroll
    for (int i = 0; i < 64; ++i) {
        const float v = h2[i];
#pragma unroll
        for (int j = 0; j < 32; ++j) o[j] = fmaf(v, W3[i * 32 + j], o[j]);
    }
#pragma unroll
    for (int j = 0; j < 32; ++j) lds[tid * 33 + j] = fmaxf(o[j], 0.f);
    __syncthreads();
    float* outb = out + (size_t)blockIdx.x * 8192;
#pragma unroll
    for (int k = 0; k < 8; ++k) {
        const int e = k * 1024 + tid * 4;
        float4 v;
        v.x = lds[((e + 0) >> 5) * 33 + ((e + 0) & 31)];
        v.y = lds[((e + 1) >> 5) * 33 + ((e + 1) & 31)];
        v.z = lds[((e + 2) >> 5) * 33 + ((e + 2) & 31)];
        v.w = lds[((e + 3) >> 5) * 33 + ((e + 3) & 31)];
        *(float4*)(outb + e) = v;
    }
}

extern "C" void kernel_launch(void* const* d_in, const int* in_sizes, int n_in,
                              void* d_out, int out_size, void* d_ws, size_t ws_size,
                              hipStream_t stream) {
    (void)in_sizes; (void)n_in; (void)out_size;

    const float* x     = (const float*)d_in[0];
    const float* table = (const float*)d_in[2];
    const float* W1    = (const float*)d_in[3];
    const float* W2    = (const float*)d_in[4];
    const float* W3    = (const float*)d_in[5];
    float* out = (float*)d_out;

    EncP p;
    const double b = exp(log(2048.0 / 16.0) / 15.0);
    for (int l = 0; l < L_LEVELS; ++l) {
        const float s = (float)(16.0 * pow(b, (double)l) - 1.0);
        p.scale[l] = s;
        p.res[l] = (unsigned)((long long)s) + 1u;
    }

    const size_t ws_needed = (size_t)L_LEVELS * N_PTS * 2 * sizeof(float); // 128 MB
    if (ws_size >= ws_needed) {
        float* ws = (float*)d_ws;
        hipLaunchKernelGGL(encode_kernel, dim3(65536), dim3(256), 0, stream,
                           x, table, ws, p);
        hipLaunchKernelGGL(mlp_kernel, dim3(N_PTS / 256), dim3(256), 0, stream,
                           ws, W1, W2, W3, out);
    } else {
        hipLaunchKernelGGL(mono_kernel, dim3(N_PTS / 256), dim3(256), 0, stream,
                           x, table, W1, W2, W3, out, p);
    }
}

// Round 4
// 796.019 us; speedup vs baseline: 4.6220x; 1.1033x over previous
//
#include <hip/hip_runtime.h>
#include <math.h>

constexpr int L_LEVELS = 16;
constexpr unsigned TABLE_SIZE = 1u << 19;
constexpr unsigned TMASK = TABLE_SIZE - 1u;
constexpr int N_PTS = 1048576;

struct EncP {
    float scale[L_LEVELS];
    unsigned res[L_LEVELS];
};

// 8-byte-aligned 4-float vector: lets the compiler emit one global_load_dwordx4
// (gfx950 supports sub-16B-aligned dwordx4) for a pair of adjacent float2
// table entries.
struct alignas(8) f4_8 { float x, y, z, w; };

// ---------------------------------------------------------------------------
// Kernel 1: grid encode, one (point, level) per thread.
// Corner pairing: dx=0/dx=1 corners are ADJACENT linear indices -> one 16B
// gather per (dy,dz) pair => 4 gathers/lane instead of 8 (TA-bound phase).
// Level-phased + XCD-pinned blockIdx decode keeps each XCD in one 4MB slice.
// ws layout: [L][N][2] floats, lane-coalesced float2 stores.
// ---------------------------------------------------------------------------
__global__ __launch_bounds__(256) void encode_kernel(
    const float* __restrict__ x,
    const float* __restrict__ table,
    float* __restrict__ ws,
    EncP p)
{
    const unsigned bid = blockIdx.x;
    const unsigned level = (bid & 7u) + 8u * (bid >> 15);
    const unsigned pblk  = (bid >> 3) & 4095u;
    const unsigned n = pblk * 256u + threadIdx.x;

    const float x0 = x[n * 3 + 0];
    const float x1 = x[n * 3 + 1];
    const float x2 = x[n * 3 + 2];

    const float s = p.scale[level];
    const unsigned r = p.res[level];
    const unsigned r2 = r * r;                   // uint32 wrap == int32 wrap bits

    float px = x0 * s + 0.5f;
    float py = x1 * s + 0.5f;
    float pz = x2 * s + 0.5f;
    float gx = floorf(px), gy = floorf(py), gz = floorf(pz);
    float fx = px - gx, fy = py - gy, fz = pz - gz;
    unsigned ix = (unsigned)(int)gx;
    unsigned iy = (unsigned)(int)gy;
    unsigned iz = (unsigned)(int)gz;
    unsigned base = ix + iy * r + iz * r2;

    const float* tl = table + (size_t)level * (size_t)TABLE_SIZE * 2u;
    const float fx1 = 1.f - fx;
    float a0 = 0.f, a1 = 0.f;
#pragma unroll
    for (int cc = 0; cc < 4; ++cc) {
        const unsigned dy = (cc >> 1) & 1u;
        const unsigned dz = cc & 1u;
        const unsigned lin0 = base + dy * r + dz * r2;   // dx=0 corner
        const unsigned idx0 = lin0 & TMASK;
        float f00, f01, f10, f11;                         // [dx][feature]
        if (idx0 != TMASK) {
            // adjacent entries: one 16B load covers dx=0 and dx=1
            const f4_8 f = *(const f4_8*)(tl + 2u * idx0);
            f00 = f.x; f01 = f.y; f10 = f.z; f11 = f.w;
        } else {
            // python mod wrap: (lin0+1) % 2^19 == 0
            const float2 a = *(const float2*)(tl + 2u * TMASK);
            const float2 b = *(const float2*)(tl);
            f00 = a.x; f01 = a.y; f10 = b.x; f11 = b.y;
        }
        const float wyz = (dy ? fy : 1.f - fy) * (dz ? fz : 1.f - fz);
        const float m0 = fmaf(fx, f10, fx1 * f00);
        const float m1 = fmaf(fx, f11, fx1 * f01);
        a0 = fmaf(wyz, m0, a0);
        a1 = fmaf(wyz, m1, a1);
    }
    *(float2*)(ws + ((size_t)level * N_PTS + n) * 2u) = make_float2(a0, a1);
}

// ---------------------------------------------------------------------------
// Kernel 2: MLP 32->64->64->32 (fp32 VALU, AGPR-backed arrays), reads xc from
// ws coalesced, writes out via padded-LDS transpose (proven 134MB WRITE_SIZE).
// ---------------------------------------------------------------------------
__global__ __launch_bounds__(256) void mlp_kernel(
    const float* __restrict__ ws,
    const float* __restrict__ W1,
    const float* __restrict__ W2,
    const float* __restrict__ W3,
    float* __restrict__ out)
{
    __shared__ float lds[256 * 33];
    const int tid = threadIdx.x;
    const unsigned n = blockIdx.x * 256u + tid;

    float xc[32];
#pragma unroll
    for (int l = 0; l < L_LEVELS; ++l) {
        const float2 v = *(const float2*)(ws + ((size_t)l * N_PTS + n) * 2u);
        xc[2 * l + 0] = v.x;
        xc[2 * l + 1] = v.y;
    }

    float h1[64];
#pragma unroll
    for (int j = 0; j < 64; ++j) h1[j] = 0.f;
#pragma unroll
    for (int i = 0; i < 32; ++i) {
        const float v = xc[i];
#pragma unroll
        for (int j = 0; j < 64; ++j) h1[j] = fmaf(v, W1[i * 64 + j], h1[j]);
    }
#pragma unroll
    for (int j = 0; j < 64; ++j) h1[j] = fmaxf(h1[j], 0.f);

    float h2[64];
#pragma unroll
    for (int j = 0; j < 64; ++j) h2[j] = 0.f;
#pragma unroll
    for (int i = 0; i < 64; ++i) {
        const float v = h1[i];
#pragma unroll
        for (int j = 0; j < 64; ++j) h2[j] = fmaf(v, W2[i * 64 + j], h2[j]);
    }
#pragma unroll
    for (int j = 0; j < 64; ++j) h2[j] = fmaxf(h2[j], 0.f);

    float o[32];
#pragma unroll
    for (int j = 0; j < 32; ++j) o[j] = 0.f;
#pragma unroll
    for (int i = 0; i < 64; ++i) {
        const float v = h2[i];
#pragma unroll
        for (int j = 0; j < 32; ++j) o[j] = fmaf(v, W3[i * 32 + j], o[j]);
    }

#pragma unroll
    for (int j = 0; j < 32; ++j) lds[tid * 33 + j] = fmaxf(o[j], 0.f);
    __syncthreads();

    float* outb = out + (size_t)blockIdx.x * 8192;
#pragma unroll
    for (int k = 0; k < 8; ++k) {
        const int e = k * 1024 + tid * 4;
        float4 v;
        v.x = lds[((e + 0) >> 5) * 33 + ((e + 0) & 31)];
        v.y = lds[((e + 1) >> 5) * 33 + ((e + 1) & 31)];
        v.z = lds[((e + 2) >> 5) * 33 + ((e + 2) & 31)];
        v.w = lds[((e + 3) >> 5) * 33 + ((e + 3) & 31)];
        *(float4*)(outb + e) = v;
    }
}

// ---------------------------------------------------------------------------
// Fallback: monolithic kernel (used only if ws too small).
// ---------------------------------------------------------------------------
__global__ __launch_bounds__(256) void mono_kernel(
    const float* __restrict__ x, const float* __restrict__ table,
    const float* __restrict__ W1, const float* __restrict__ W2,
    const float* __restrict__ W3, float* __restrict__ out, EncP p)
{
    __shared__ float lds[256 * 33];
    const int tid = threadIdx.x;
    const int n = blockIdx.x * 256 + tid;
    const float x0 = x[n * 3 + 0], x1 = x[n * 3 + 1], x2 = x[n * 3 + 2];
    float xc[32];
#pragma unroll
    for (int l = 0; l < L_LEVELS; ++l) {
        const float s = p.scale[l];
        const unsigned r = p.res[l], r2 = r * r;
        float px = x0 * s + 0.5f, py = x1 * s + 0.5f, pz = x2 * s + 0.5f;
        float gx = floorf(px), gy = floorf(py), gz = floorf(pz);
        float fx = px - gx, fy = py - gy, fz = pz - gz;
        unsigned base = (unsigned)(int)gx + (unsigned)(int)gy * r + (unsigned)(int)gz * r2;
        const float* tl = table + (size_t)l * (size_t)TABLE_SIZE * 2u;
        float a0 = 0.f, a1 = 0.f;
#pragma unroll
        for (int c = 0; c < 8; ++c) {
            const unsigned dx = (c >> 2) & 1u, dy = (c >> 1) & 1u, dz = c & 1u;
            unsigned idx = (base + dx + dy * r + dz * r2) & TMASK;
            const float2 f = *(const float2*)(tl + 2u * idx);
            const float w = (dx ? fx : 1.f - fx) * (dy ? fy : 1.f - fy) * (dz ? fz : 1.f - fz);
            a0 += w * f.x; a1 += w * f.y;
        }
        xc[2 * l] = a0; xc[2 * l + 1] = a1;
    }
    float h1[64];
#pragma unroll
    for (int j = 0; j < 64; ++j) h1[j] = 0.f;
#pragma unroll
    for (int i = 0; i < 32; ++i) {
        const float v = xc[i];
#pragma unroll
        for (int j = 0; j < 64; ++j) h1[j] = fmaf(v, W1[i * 64 + j], h1[j]);
    }
#pragma unroll
    for (int j = 0; j < 64; ++j) h1[j] = fmaxf(h1[j], 0.f);
    float h2[64];
#pragma unroll
    for (int j = 0; j < 64; ++j) h2[j] = 0.f;
#pragma unroll
    for (int i = 0; i < 64; ++i) {
        const float v = h1[i];
#pragma unroll
        for (int j = 0; j < 64; ++j) h2[j] = fmaf(v, W2[i * 64 + j], h2[j]);
    }
#pragma unroll
    for (int j = 0; j < 64; ++j) h2[j] = fmaxf(h2[j], 0.f);
    float o[32];
#pragma unroll
    for (int j = 0; j < 32; ++j) o[j] = 0.f;
#pragma unroll
    for (int i = 0; i < 64; ++i) {
        const float v = h2[i];
#pragma unroll
        for (int j = 0; j < 32; ++j) o[j] = fmaf(v, W3[i * 32 + j], o[j]);
    }
#pragma unroll
    for (int j = 0; j < 32; ++j) lds[tid * 33 + j] = fmaxf(o[j], 0.f);
    __syncthreads();
    float* outb = out + (size_t)blockIdx.x * 8192;
#pragma unroll
    for (int k = 0; k < 8; ++k) {
        const int e = k * 1024 + tid * 4;
        float4 v;
        v.x = lds[((e + 0) >> 5) * 33 + ((e + 0) & 31)];
        v.y = lds[((e + 1) >> 5) * 33 + ((e + 1) & 31)];
        v.z = lds[((e + 2) >> 5) * 33 + ((e + 2) & 31)];
        v.w = lds[((e + 3) >> 5) * 33 + ((e + 3) & 31)];
        *(float4*)(outb + e) = v;
    }
}

extern "C" void kernel_launch(void* const* d_in, const int* in_sizes, int n_in,
                              void* d_out, int out_size, void* d_ws, size_t ws_size,
                              hipStream_t stream) {
    (void)in_sizes; (void)n_in; (void)out_size;

    const float* x     = (const float*)d_in[0];
    const float* table = (const float*)d_in[2];
    const float* W1    = (const float*)d_in[3];
    const float* W2    = (const float*)d_in[4];
    const float* W3    = (const float*)d_in[5];
    float* out = (float*)d_out;

    EncP p;
    const double b = exp(log(2048.0 / 16.0) / 15.0);
    for (int l = 0; l < L_LEVELS; ++l) {
        const float s = (float)(16.0 * pow(b, (double)l) - 1.0);
        p.scale[l] = s;
        p.res[l] = (unsigned)((long long)s) + 1u;
    }

    const size_t ws_needed = (size_t)L_LEVELS * N_PTS * 2 * sizeof(float); // 128 MB
    if (ws_size >= ws_needed) {
        float* ws = (float*)d_ws;
        hipLaunchKernelGGL(encode_kernel, dim3(65536), dim3(256), 0, stream,
                           x, table, ws, p);
        hipLaunchKernelGGL(mlp_kernel, dim3(N_PTS / 256), dim3(256), 0, stream,
                           ws, W1, W2, W3, out);
    } else {
        hipLaunchKernelGGL(mono_kernel, dim3(N_PTS / 256), dim3(256), 0, stream,
                           x, table, W1, W2, W3, out, p);
    }
}

// Round 5
// 498.476 us; speedup vs baseline: 7.3809x; 1.5969x over previous
//
#include <hip/hip_runtime.h>
#include <hip/hip_bf16.h>
#include <math.h>

constexpr int L_LEVELS = 16;
constexpr unsigned TABLE_SIZE = 1u << 19;
constexpr unsigned TMASK = TABLE_SIZE - 1u;
constexpr int N_PTS = 1048576;

typedef __bf16 bf16x8 __attribute__((ext_vector_type(8)));
typedef float f32x4 __attribute__((ext_vector_type(4)));

struct EncP {
    float scale[L_LEVELS];
    unsigned res[L_LEVELS];
};

struct alignas(8) f4_8 { float x, y, z, w; };

// ---------------------------------------------------------------------------
// Kernel 1: grid encode, one (point, level) per thread. Corner-paired 16B
// gathers (4/lane), level-phased XCD-pinned blockIdx decode (R3/R4 proven).
// NEW: output packed bf16 pair per (level,point): ws[L][N] u32, coalesced.
// ---------------------------------------------------------------------------
__global__ __launch_bounds__(256) void encode_kernel(
    const float* __restrict__ x,
    const float* __restrict__ table,
    unsigned* __restrict__ wsu,
    EncP p)
{
    const unsigned bid = blockIdx.x;
    const unsigned level = (bid & 7u) + 8u * (bid >> 15);
    const unsigned pblk  = (bid >> 3) & 4095u;
    const unsigned n = pblk * 256u + threadIdx.x;

    const float x0 = x[n * 3 + 0];
    const float x1 = x[n * 3 + 1];
    const float x2 = x[n * 3 + 2];

    const float s = p.scale[level];
    const unsigned r = p.res[level];
    const unsigned r2 = r * r;                   // uint32 wrap == int32 wrap bits

    float px = x0 * s + 0.5f;
    float py = x1 * s + 0.5f;
    float pz = x2 * s + 0.5f;
    float gx = floorf(px), gy = floorf(py), gz = floorf(pz);
    float fx = px - gx, fy = py - gy, fz = pz - gz;
    unsigned ix = (unsigned)(int)gx;
    unsigned iy = (unsigned)(int)gy;
    unsigned iz = (unsigned)(int)gz;
    unsigned base = ix + iy * r + iz * r2;

    const float* tl = table + (size_t)level * (size_t)TABLE_SIZE * 2u;
    const float fx1 = 1.f - fx;
    float a0 = 0.f, a1 = 0.f;
#pragma unroll
    for (int cc = 0; cc < 4; ++cc) {
        const unsigned dy = (cc >> 1) & 1u;
        const unsigned dz = cc & 1u;
        const unsigned lin0 = base + dy * r + dz * r2;   // dx=0 corner
        const unsigned idx0 = lin0 & TMASK;
        float f00, f01, f10, f11;
        if (idx0 != TMASK) {
            const f4_8 f = *(const f4_8*)(tl + 2u * idx0);
            f00 = f.x; f01 = f.y; f10 = f.z; f11 = f.w;
        } else {
            const float2 a = *(const float2*)(tl + 2u * TMASK);
            const float2 b = *(const float2*)(tl);
            f00 = a.x; f01 = a.y; f10 = b.x; f11 = b.y;
        }
        const float wyz = (dy ? fy : 1.f - fy) * (dz ? fz : 1.f - fz);
        const float m0 = fmaf(fx, f10, fx1 * f00);
        const float m1 = fmaf(fx, f11, fx1 * f01);
        a0 = fmaf(wyz, m0, a0);
        a1 = fmaf(wyz, m1, a1);
    }
    __hip_bfloat162 hv = __float22bfloat162_rn(make_float2(a0, a1));
    unsigned u;
    __builtin_memcpy(&u, &hv, 4);
    wsu[(size_t)level * N_PTS + n] = u;   // coalesced u32
}

// ---------------------------------------------------------------------------
// Kernel 2: MFMA MLP 32->64->64->32 (bf16 in, fp32 accum).
// Block = 4 waves, 64 points/iter, 8 iters. Per wave: 16 rows.
//   A-frag: A[row=l&15][k=(l>>4)*8+e]   (8 consecutive bf16 -> ds_read_b128)
//   B-frag: B[k=(l>>4)*8+e][col=l&15]   (gathered from fp32 W, once/block)
//   D:      col=l&15, row=(l>>4)*4+reg  (verified m89)
// H1/H2 are per-wave-private LDS regions (wave reads only rows it wrote).
// ---------------------------------------------------------------------------
__global__ __launch_bounds__(256) void mlp_mfma_kernel(
    const unsigned* __restrict__ wsu,
    const float* __restrict__ W1,
    const float* __restrict__ W2,
    const float* __restrict__ W3,
    float* __restrict__ out)
{
    __shared__ __align__(16) unsigned short xin[64 * 40];   // [pt][feat] pad 40
    __shared__ __align__(16) unsigned short H1[64 * 72];    // [pt][feat] pad 72
    __shared__ __align__(16) unsigned short H2[64 * 72];

    const int tid = threadIdx.x;
    const int l  = tid & 63;
    const int w  = tid >> 6;
    const int lr = l & 15;    // frag row (A) / col (B,D)
    const int lg = l >> 4;    // k-group

    // ---- weight fragments, built once per block (L2-hit gathers) ----
    bf16x8 b1[4], b2[4][2], b3[2][2];
#pragma unroll
    for (int cb = 0; cb < 4; ++cb)
#pragma unroll
        for (int e = 0; e < 8; ++e)
            b1[cb][e] = (__bf16)W1[(lg * 8 + e) * 64 + cb * 16 + lr];
#pragma unroll
    for (int cb = 0; cb < 4; ++cb)
#pragma unroll
        for (int kh = 0; kh < 2; ++kh)
#pragma unroll
            for (int e = 0; e < 8; ++e)
                b2[cb][kh][e] = (__bf16)W2[(kh * 32 + lg * 8 + e) * 64 + cb * 16 + lr];
#pragma unroll
    for (int cb = 0; cb < 2; ++cb)
#pragma unroll
        for (int kh = 0; kh < 2; ++kh)
#pragma unroll
            for (int e = 0; e < 8; ++e)
                b3[cb][kh][e] = (__bf16)W3[(kh * 32 + lg * 8 + e) * 32 + cb * 16 + lr];

    constexpr int ITERS = 8;
    const int tile0 = blockIdx.x * ITERS;
    const f32x4 z = {0.f, 0.f, 0.f, 0.f};

    for (int it = 0; it < ITERS; ++it) {
        const int p0 = (tile0 + it) * 64;

        // ---- stage 64 points x 32 feats into LDS (coalesced u32 loads) ----
        {
            const int i  = tid & 63;
            const int lb = tid >> 6;
#pragma unroll
            for (int ps = 0; ps < 4; ++ps) {
                const int lev = ps * 4 + lb;
                const unsigned v = wsu[(size_t)lev * N_PTS + p0 + i];
                *(unsigned*)&xin[i * 40 + 2 * lev] = v;  // feats 2lev,2lev+1
            }
        }
        __syncthreads();

        const int row = w * 16 + lr;

        // ---- layer 1: [16x32] @ [32x64] ----
        const bf16x8 a1 = *(const bf16x8*)&xin[row * 40 + lg * 8];
        f32x4 d1[4];
#pragma unroll
        for (int cb = 0; cb < 4; ++cb)
            d1[cb] = __builtin_amdgcn_mfma_f32_16x16x32_bf16(a1, b1[cb], z, 0, 0, 0);
#pragma unroll
        for (int cb = 0; cb < 4; ++cb)
#pragma unroll
            for (int reg = 0; reg < 4; ++reg) {
                const __bf16 hv = (__bf16)fmaxf(d1[cb][reg], 0.f);
                unsigned short bits;
                __builtin_memcpy(&bits, &hv, 2);
                H1[(w * 16 + lg * 4 + reg) * 72 + cb * 16 + lr] = bits;
            }

        // ---- layer 2: [16x64] @ [64x64] (same-wave LDS RAW: in-order DS) ----
        const bf16x8 a2_0 = *(const bf16x8*)&H1[row * 72 + lg * 8];
        const bf16x8 a2_1 = *(const bf16x8*)&H1[row * 72 + 32 + lg * 8];
        f32x4 d2[4];
#pragma unroll
        for (int cb = 0; cb < 4; ++cb) {
            f32x4 t = __builtin_amdgcn_mfma_f32_16x16x32_bf16(a2_0, b2[cb][0], z, 0, 0, 0);
            d2[cb]  = __builtin_amdgcn_mfma_f32_16x16x32_bf16(a2_1, b2[cb][1], t, 0, 0, 0);
        }
#pragma unroll
        for (int cb = 0; cb < 4; ++cb)
#pragma unroll
            for (int reg = 0; reg < 4; ++reg) {
                const __bf16 hv = (__bf16)fmaxf(d2[cb][reg], 0.f);
                unsigned short bits;
                __builtin_memcpy(&bits, &hv, 2);
                H2[(w * 16 + lg * 4 + reg) * 72 + cb * 16 + lr] = bits;
            }

        // ---- layer 3: [16x64] @ [64x32] ----
        const bf16x8 a3_0 = *(const bf16x8*)&H2[row * 72 + lg * 8];
        const bf16x8 a3_1 = *(const bf16x8*)&H2[row * 72 + 32 + lg * 8];
        f32x4 d3[2];
#pragma unroll
        for (int cb = 0; cb < 2; ++cb) {
            f32x4 t = __builtin_amdgcn_mfma_f32_16x16x32_bf16(a3_0, b3[cb][0], z, 0, 0, 0);
            d3[cb]  = __builtin_amdgcn_mfma_f32_16x16x32_bf16(a3_1, b3[cb][1], t, 0, 0, 0);
        }

        // ---- store: 16-lane groups write 64B runs (coalesced dwords) ----
        float* ob = out + ((size_t)p0 + w * 16) * 32;
#pragma unroll
        for (int cb = 0; cb < 2; ++cb)
#pragma unroll
            for (int reg = 0; reg < 4; ++reg)
                ob[(lg * 4 + reg) * 32 + cb * 16 + lr] = fmaxf(d3[cb][reg], 0.f);

        __syncthreads();   // protect xin before next iter's staging
    }
}

// ---------------------------------------------------------------------------
// Fallback: monolithic fp32 kernel (used only if ws too small).
// ---------------------------------------------------------------------------
__global__ __launch_bounds__(256) void mono_kernel(
    const float* __restrict__ x, const float* __restrict__ table,
    const float* __restrict__ W1, const float* __restrict__ W2,
    const float* __restrict__ W3, float* __restrict__ out, EncP p)
{
    __shared__ float lds[256 * 33];
    const int tid = threadIdx.x;
    const int n = blockIdx.x * 256 + tid;
    const float x0 = x[n * 3 + 0], x1 = x[n * 3 + 1], x2 = x[n * 3 + 2];
    float xc[32];
#pragma unroll
    for (int l = 0; l < L_LEVELS; ++l) {
        const float s = p.scale[l];
        const unsigned r = p.res[l], r2 = r * r;
        float px = x0 * s + 0.5f, py = x1 * s + 0.5f, pz = x2 * s + 0.5f;
        float gx = floorf(px), gy = floorf(py), gz = floorf(pz);
        float fx = px - gx, fy = py - gy, fz = pz - gz;
        unsigned base = (unsigned)(int)gx + (unsigned)(int)gy * r + (unsigned)(int)gz * r2;
        const float* tl = table + (size_t)l * (size_t)TABLE_SIZE * 2u;
        float a0 = 0.f, a1 = 0.f;
#pragma unroll
        for (int c = 0; c < 8; ++c) {
            const unsigned dx = (c >> 2) & 1u, dy = (c >> 1) & 1u, dz = c & 1u;
            unsigned idx = (base + dx + dy * r + dz * r2) & TMASK;
            const float2 f = *(const float2*)(tl + 2u * idx);
            const float w = (dx ? fx : 1.f - fx) * (dy ? fy : 1.f - fy) * (dz ? fz : 1.f - fz);
            a0 += w * f.x; a1 += w * f.y;
        }
        xc[2 * l] = a0; xc[2 * l + 1] = a1;
    }
    float h1[64];
#pragma unroll
    for (int j = 0; j < 64; ++j) h1[j] = 0.f;
#pragma unroll
    for (int i = 0; i < 32; ++i) {
        const float v = xc[i];
#pragma unroll
        for (int j = 0; j < 64; ++j) h1[j] = fmaf(v, W1[i * 64 + j], h1[j]);
    }
#pragma unroll
    for (int j = 0; j < 64; ++j) h1[j] = fmaxf(h1[j], 0.f);
    float h2[64];
#pragma unroll
    for (int j = 0; j < 64; ++j) h2[j] = 0.f;
#pragma unroll
    for (int i = 0; i < 64; ++i) {
        const float v = h1[i];
#pragma unroll
        for (int j = 0; j < 64; ++j) h2[j] = fmaf(v, W2[i * 64 + j], h2[j]);
    }
#pragma unroll
    for (int j = 0; j < 64; ++j) h2[j] = fmaxf(h2[j], 0.f);
    float o[32];
#pragma unroll
    for (int j = 0; j < 32; ++j) o[j] = 0.f;
#pragma unroll
    for (int i = 0; i < 64; ++i) {
        const float v = h2[i];
#pragma unroll
        for (int j = 0; j < 32; ++j) o[j] = fmaf(v, W3[i * 32 + j], o[j]);
    }
#pragma unroll
    for (int j = 0; j < 32; ++j) lds[tid * 33 + j] = fmaxf(o[j], 0.f);
    __syncthreads();
    float* outb = out + (size_t)blockIdx.x * 8192;
#pragma unroll
    for (int k = 0; k < 8; ++k) {
        const int e = k * 1024 + tid * 4;
        float4 v;
        v.x = lds[((e + 0) >> 5) * 33 + ((e + 0) & 31)];
        v.y = lds[((e + 1) >> 5) * 33 + ((e + 1) & 31)];
        v.z = lds[((e + 2) >> 5) * 33 + ((e + 2) & 31)];
        v.w = lds[((e + 3) >> 5) * 33 + ((e + 3) & 31)];
        *(float4*)(outb + e) = v;
    }
}

extern "C" void kernel_launch(void* const* d_in, const int* in_sizes, int n_in,
                              void* d_out, int out_size, void* d_ws, size_t ws_size,
                              hipStream_t stream) {
    (void)in_sizes; (void)n_in; (void)out_size;

    const float* x     = (const float*)d_in[0];
    const float* table = (const float*)d_in[2];
    const float* W1    = (const float*)d_in[3];
    const float* W2    = (const float*)d_in[4];
    const float* W3    = (const float*)d_in[5];
    float* out = (float*)d_out;

    EncP p;
    const double b = exp(log(2048.0 / 16.0) / 15.0);
    for (int l = 0; l < L_LEVELS; ++l) {
        const float s = (float)(16.0 * pow(b, (double)l) - 1.0);
        p.scale[l] = s;
        p.res[l] = (unsigned)((long long)s) + 1u;
    }

    const size_t ws_needed = (size_t)L_LEVELS * N_PTS * sizeof(unsigned); // 64 MB
    if (ws_size >= ws_needed) {
        unsigned* wsu = (unsigned*)d_ws;
        hipLaunchKernelGGL(encode_kernel, dim3(65536), dim3(256), 0, stream,
                           x, table, wsu, p);
        hipLaunchKernelGGL(mlp_mfma_kernel, dim3(2048), dim3(256), 0, stream,
                           wsu, W1, W2, W3, out);
    } else {
        hipLaunchKernelGGL(mono_kernel, dim3(N_PTS / 256), dim3(256), 0, stream,
                           x, table, W1, W2, W3, out, p);
    }
}